// Round 15
// baseline (81.819 us; speedup 1.0000x reference)
//
#include <hip/hip_runtime.h>

// SbS hidden dynamics: per-pixel serial scan over T spikes.
#define BB      16
#define TT      128
#define XDIM    16
#define YDIM    16
#define IN_DIM  256
#define H_DIM   64
#define XY      (XDIM*YDIM)

// Round-15: break the per-step serial chain. R14's TLP null result (2 waves/
// SIMD, no gain) proves the wall is per-step dependency LATENCY: all pixels
// already concurrent, wall = 128 x chain. Old chain: h -> h*w -> 4-hop DPP
// reduce -> rcp -> h' (reduce and rcp in SERIES). New: track s by the exact
// identity  s' = rd*A + (erd*rs)*B + erdf*C',  A = Sum(h*w'), B = Sum(ht*w'),
// C' = rowsum(weights[sp']) (256-entry table, prologue). A,B reduces start at
// h_t (don't wait for rs_t); rcp(s_t) runs IN PARALLEL with them. Two DPP
// chains interleave -> overlapped latency. s_0 = C_0/64 (h_init uniform).
// h-update unchanged (R11/12-validated: no guard, raw rcp on s, NR on rd).
// Numerics: identity is exact; A,B are fresh reduces of h each step -> s
// error does not compound; rs raw-rcp error ~1e-5 enters via eps-scaled term.
// Layout (R12, best measured): 4 px/wave, one per 16-lane DPP row, float4 h
// per lane; reduce quad_perm 0xB1/0x4E + row_ror 0x124/0x128 (validated).
// Weights prefetched 2 groups (8 steps) ahead; P (rd,erd,erdf,erdf*C') one
// float4 per step, read 2 groups ahead. 256 blocks = 1/CU, 1024 waves.

#define DPP_ADD(v, ctrl)                                                      \
    v += __int_as_float(__builtin_amdgcn_update_dpp(                          \
        0, __float_as_int(v), (ctrl), 0xf, 0xf, true))

// one scan step with s-recurrence lookahead.
// WQ = w_t row frag, WN = w_{t+1} row frag, P = (rd, erd, erdf, erdf*C_{t+1})
// carries: h (float4), rs (= 1/s_t on entry, 1/s_{t+1} on exit)
#define STEP(WQ, WN, P)                                                       \
    {                                                                         \
        const float ht0 = h.x * (WQ).x;                                       \
        const float ht1 = h.y * (WQ).y;                                       \
        const float ht2 = h.z * (WQ).z;                                       \
        const float ht3 = h.w * (WQ).w;                                       \
        const float a0 = h.x * (WN).x;                                        \
        const float a1 = h.y * (WN).y;                                        \
        const float a2 = h.z * (WN).z;                                        \
        const float a3 = h.w * (WN).w;                                        \
        const float b0 = ht0 * (WN).x;                                        \
        const float b1 = ht1 * (WN).y;                                        \
        const float b2 = ht2 * (WN).z;                                        \
        const float b3 = ht3 * (WN).w;                                        \
        float rA = (a0 + a1) + (a2 + a3);                                     \
        float rB = (b0 + b1) + (b2 + b3);                                     \
        DPP_ADD(rA, 0xB1);  DPP_ADD(rB, 0xB1);   /* quad_perm xor1 */         \
        DPP_ADD(rA, 0x4E);  DPP_ADD(rB, 0x4E);   /* quad_perm xor2 */         \
        DPP_ADD(rA, 0x124); DPP_ADD(rB, 0x124);  /* row_ror:4 */              \
        DPP_ADD(rA, 0x128); DPP_ADD(rB, 0x128);  /* row_ror:8 -> full sums */ \
        const float k2  = (P).y * rs;            /* erd/s_t */                \
        const float t30 = fmaf(h.x, (P).x, (P).z);                            \
        const float t31 = fmaf(h.y, (P).x, (P).z);                            \
        const float t32 = fmaf(h.z, (P).x, (P).z);                            \
        const float t33 = fmaf(h.w, (P).x, (P).z);                            \
        h.x = fmaf(k2, ht0, t30);                                             \
        h.y = fmaf(k2, ht1, t31);                                             \
        h.z = fmaf(k2, ht2, t32);                                             \
        h.w = fmaf(k2, ht3, t33);                                             \
        const float sn = fmaf((P).x, rA, fmaf(k2, rB, (P).w));                \
        rs = __builtin_amdgcn_rcpf(sn);          /* 1/s_{t+1} */              \
    }

__global__ __launch_bounds__(256) void sbs_scan_kernel(
    const int*   __restrict__ spikes,   // [B,T,X,Y]
    const float* __restrict__ eps_xy,   // [IN,X,Y]
    const float* __restrict__ eps_t,    // [T]
    const float* __restrict__ weights,  // [IN,H]
    const float* __restrict__ h_init,   // [H]
    const float* __restrict__ fo_ptr,   // [1]
    float*       __restrict__ out)      // [B,H,X,Y]
{
    __shared__ int4   s_spk4[YDIM][TT / 4 + 1];   //  8.4 KB spikes, 4/entry
    __shared__ float4 s_P4[YDIM][TT + 1];         // 33 KB per-step scalars
    __shared__ float  s_Cs[IN_DIM];               //  1 KB row sums
    __shared__ float  s_out[YDIM][H_DIM + 1];     //  4.2 KB transpose

    const int tid = threadIdx.x;
    const int bi  = blockIdx.x;      // 256 blocks
    const int b   = bi >> 4;         // 16
    const int x   = bi & 15;         // 16 (block covers all 16 y)

    // ---- stage spikes: 2048 ints, 8/thread (kept in regs for P pass) ----
    int spv[8];
    #pragma unroll
    for (int k = 0; k < 8; ++k) {
        const int idx = tid + k * 256;
        const int t = idx >> 4, yy = idx & 15;
        const int sp = spikes[(b * TT + t) * XY + x * YDIM + yy];
        spv[k] = sp;
        ((int*)s_spk4[yy])[t] = sp;
    }

    // ---- weight row-sums: thread i sums row i (IN_DIM==256==blockDim) ----
    {
        const float4* wr = (const float4*)weights + tid * 16;
        float c0 = 0.f, c1 = 0.f, c2 = 0.f, c3 = 0.f;
        #pragma unroll
        for (int j = 0; j < 16; ++j) {
            const float4 v = wr[j];
            c0 += v.x; c1 += v.y; c2 += v.z; c3 += v.w;
        }
        s_Cs[tid] = (c0 + c1) + (c2 + c3);
    }
    __syncthreads();

    const float fo   = fo_ptr[0];
    const float fo1  = 1.0f + fo;
    const float fo_h = fo * (1.0f / (float)H_DIM);

    // ---- per-step scalars: (rd, erd, erdf, erdf*Csum[sp_{t+1}]) ----
    #pragma unroll
    for (int k = 0; k < 8; ++k) {
        const int idx = tid + k * 256;
        const int t = idx >> 4, yy = idx & 15;
        const float eps = eps_xy[spv[k] * XY + x * YDIM + yy] * eps_t[t];
        const float den = fmaf(eps, fo1, 1.0f);
        float rd = __builtin_amdgcn_rcpf(den);
        rd = fmaf(rd, fmaf(-den, rd, 1.0f), rd);          // Newton (off-chain)
        const float erd  = eps * rd;
        const float erdf = erd * fo_h;
        const int   spn  = ((const int*)s_spk4[yy])[(t + 1) & (TT - 1)];
        s_P4[yy][t] = make_float4(rd, erd, erdf, erdf * s_Cs[spn]);
    }
    __syncthreads();

    // ---- per-lane geometry: row = pixel, 4 h-elems/lane (R12) ----
    const int wave = tid >> 6;
    const int lane = tid & 63;
    const int row  = lane >> 4;          // 0..3
    const int il   = lane & 15;          // 0..15
    const int y    = wave * 4 + row;     // pixel y

    const float4* __restrict__ w4 = (const float4*)weights;  // [IN][16]
    const int4*   __restrict__ Sy = s_spk4[y];
    const float4* __restrict__ Py = s_P4[y];

    float4 h = ((const float4*)h_init)[il];

    // ---- queues: weights 2 groups ahead; P 2 groups ahead ----
    const int4 s0 = Sy[0];
    const int4 s1 = Sy[1];
    int4 sB = Sy[2];                     // indices for group g+2 loads
    float4 cur0 = w4[s0.x * 16 + il], cur1 = w4[s0.y * 16 + il];
    float4 cur2 = w4[s0.z * 16 + il], cur3 = w4[s0.w * 16 + il];
    float4 nxt0 = w4[s1.x * 16 + il], nxt1 = w4[s1.y * 16 + il];
    float4 nxt2 = w4[s1.z * 16 + il], nxt3 = w4[s1.w * 16 + il];
    float4 PA0 = Py[0], PA1 = Py[1], PA2 = Py[2], PA3 = Py[3];
    float4 PB0 = Py[4], PB1 = Py[5], PB2 = Py[6], PB3 = Py[7];

    // s_0 = Sum(h0 * w0) = Csum[sp0]/64 (h_init uniform 1/64)
    float rs = __builtin_amdgcn_rcpf(s_Cs[s0.x] * (1.0f / 64.0f));

    #pragma unroll 2
    for (int g = 0; g < TT / 4; ++g) {
        // prefetches (wrap at tail: valid rows, results dead)
        const int4   s_in = Sy[(g + 3) & 31];
        const float4 p0 = Py[(4 * g + 8)  & 127];
        const float4 p1 = Py[(4 * g + 9)  & 127];
        const float4 p2 = Py[(4 * g + 10) & 127];
        const float4 p3 = Py[(4 * g + 11) & 127];
        const float4 wl0 = w4[sB.x * 16 + il];   // rows for group g+2
        const float4 wl1 = w4[sB.y * 16 + il];
        const float4 wl2 = w4[sB.z * 16 + il];
        const float4 wl3 = w4[sB.w * 16 + il];

        STEP(cur0, cur1, PA0);
        STEP(cur1, cur2, PA1);
        STEP(cur2, cur3, PA2);
        STEP(cur3, nxt0, PA3);

        cur0 = nxt0; cur1 = nxt1; cur2 = nxt2; cur3 = nxt3;
        nxt0 = wl0;  nxt1 = wl1;  nxt2 = wl2;  nxt3 = wl3;
        PA0 = PB0; PA1 = PB1; PA2 = PB2; PA3 = PB3;
        PB0 = p0;  PB1 = p1;  PB2 = p2;  PB3 = p3;
        sB = s_in;
    }

    // ---- output transpose: out[b, h, x, y] ----
    *(float4*)&s_out[y][4 * il] = h;
    __syncthreads();
    #pragma unroll
    for (int k = 0; k < 4; ++k) {
        const int idx = tid + k * 256;   // 1024 = 64 h * 16 y
        const int hh = idx >> 4, yy = idx & 15;
        out[b * (H_DIM * XY) + hh * XY + x * YDIM + yy] = s_out[yy][hh];
    }
}

extern "C" void kernel_launch(void* const* d_in, const int* in_sizes, int n_in,
                              void* d_out, int out_size, void* d_ws, size_t ws_size,
                              hipStream_t stream) {
    // inputs (setup_inputs order):
    // 0: input [B,IN,X,Y] f32 (unused)   1: spikes [B,T,X,Y] i32
    // 2: epsilon_xy [IN,X,Y] f32         3: epsilon_t_0 [T] f32
    // 4: weights [IN,H] f32              5: h_initial [H] f32
    // 6: forgetting_offset [1] f32
    const int*   spikes  = (const int*)  d_in[1];
    const float* eps_xy  = (const float*)d_in[2];
    const float* eps_t   = (const float*)d_in[3];
    const float* weights = (const float*)d_in[4];
    const float* h_init  = (const float*)d_in[5];
    const float* fo_ptr  = (const float*)d_in[6];
    float*       out     = (float*)d_out;

    const int grid = BB * XDIM;   // 256 blocks, 16 pixels each
    sbs_scan_kernel<<<grid, 256, 0, stream>>>(
        spikes, eps_xy, eps_t, weights, h_init, fo_ptr, out);
}

// Round 16
// 76.301 us; speedup vs baseline: 1.0723x; 1.0723x over previous
//
#include <hip/hip_runtime.h>

// SbS hidden dynamics: per-pixel serial scan over T spikes.
#define BB      16
#define TT      128
#define XDIM    16
#define YDIM    16
#define IN_DIM  256
#define H_DIM   64
#define XY      (XDIM*YDIM)

// Round-16 = R12 (best measured, 77.0us) + weights table staged in LDS.
// Evidence: wall ~300cyc/step survives chain-shortening (R15 null) AND
// 2x TLP (R14 null) -> not VALU chain, not issue. Remaining suspect: the
// weight gather path. 64KB table > 32KB L1 -> ~50% miss to L2 (~200cyc);
// covering needs 100s of outstanding lines but L1 in-flight-miss (MSHR)
// limits cap it -> sustainable rate ~300cyc/step, indifferent to wave
// count and chain length == all observations. Fix: weights in LDS (no
// MSHR, ds_read_b128 ~12cyc throughput). Static LDS ~93KB, 1 block/CU
// (precedent: learn_hip m201 example uses 128KB static).
// Everything else identical to R12: 4 px/wave (one per 16-lane DPP row),
// float4 h/lane; reduce quad_perm 0xB1/0x4E + row_ror 0x124/0x128; math
// validated R11/12 (no s-guard, raw rcp on s, NR on rd); spikes int4 +
// P float4 group-batched LDS reads; weight rows prefetched 1 group ahead.

#define DPP_ADD(v, ctrl)                                                      \
    v += __int_as_float(__builtin_amdgcn_update_dpp(                          \
        0, __float_as_int(v), (ctrl), 0xf, 0xf, true))

// one scan step; reads/writes h (float4), uses W (float4), RD/ERD scalars
#define STEP(W, RD, ERD)                                                      \
    {                                                                         \
        const float ht0 = h.x * (W).x;                                        \
        const float ht1 = h.y * (W).y;                                        \
        const float ht2 = h.z * (W).z;                                        \
        const float ht3 = h.w * (W).w;                                        \
        float r = (ht0 + ht1) + (ht2 + ht3);                                  \
        const float erdf = (ERD) * fo_h;                                      \
        const float eht0 = (ERD) * ht0;                                       \
        const float eht1 = (ERD) * ht1;                                       \
        const float eht2 = (ERD) * ht2;                                       \
        const float eht3 = (ERD) * ht3;                                       \
        const float t30 = fmaf(h.x, (RD), erdf);                              \
        const float t31 = fmaf(h.y, (RD), erdf);                              \
        const float t32 = fmaf(h.z, (RD), erdf);                              \
        const float t33 = fmaf(h.w, (RD), erdf);                              \
        DPP_ADD(r, 0xB1);   /* quad_perm xor1 */                              \
        DPP_ADD(r, 0x4E);   /* quad_perm xor2 -> quad sums */                 \
        DPP_ADD(r, 0x124);  /* row_ror:4 */                                   \
        DPP_ADD(r, 0x128);  /* row_ror:8 -> full 64-elem sum */               \
        const float rs = __builtin_amdgcn_rcpf(r); /* s>=1e-3 structurally */ \
        h.x = fmaf(rs, eht0, t30);                                            \
        h.y = fmaf(rs, eht1, t31);                                            \
        h.z = fmaf(rs, eht2, t32);                                            \
        h.w = fmaf(rs, eht3, t33);                                            \
    }

__global__ __launch_bounds__(256) void sbs_scan_kernel(
    const int*   __restrict__ spikes,   // [B,T,X,Y]
    const float* __restrict__ eps_xy,   // [IN,X,Y]
    const float* __restrict__ eps_t,    // [T]
    const float* __restrict__ weights,  // [IN,H]
    const float* __restrict__ h_init,   // [H]
    const float* __restrict__ fo_ptr,   // [1]
    float*       __restrict__ out)      // [B,H,X,Y]
{
    __shared__ float4 s_w4[IN_DIM * 16];          // 64 KB weights table
    __shared__ int4   s_spk4[YDIM][TT / 4 + 1];   // 8.4 KB spikes, 4/entry
    __shared__ float4 s_P4[YDIM][TT / 2 + 1];     // 16.6 KB (rd,erd)x2
    __shared__ float  s_out[YDIM][H_DIM + 1];     // 4.2 KB transpose

    const int tid = threadIdx.x;
    const int bi  = blockIdx.x;      // 256 blocks = 1/CU
    const int b   = bi >> 4;         // 16
    const int x   = bi & 15;         // 16 (block covers all 16 y)

    // ---- stage weights -> LDS (coalesced: 16 float4/thread) ----
    {
        const float4* __restrict__ w4g = (const float4*)weights;
        #pragma unroll
        for (int k = 0; k < 16; ++k)
            s_w4[tid + k * 256] = w4g[tid + k * 256];
    }

    // ---- stage spikes: 2048 ints, 8/thread (kept in regs for P pass) ----
    int spv[8];
    #pragma unroll
    for (int k = 0; k < 8; ++k) {
        const int idx = tid + k * 256;      // t = idx>>4, y = idx&15
        const int t = idx >> 4, yy = idx & 15;
        const int sp = spikes[(b * TT + t) * XY + x * YDIM + yy];
        spv[k] = sp;
        ((int*)s_spk4[yy])[t] = sp;
    }

    const float fo   = fo_ptr[0];
    const float fo1  = 1.0f + fo;
    const float fo_h = fo * (1.0f / (float)H_DIM);

    // ---- per-step scalars: rd = 1/(1+eps(1+fo)) (NR, off-chain), erd ----
    #pragma unroll
    for (int k = 0; k < 8; ++k) {
        const int idx = tid + k * 256;
        const int t = idx >> 4, yy = idx & 15;
        const float eps = eps_xy[spv[k] * XY + x * YDIM + yy] * eps_t[t];
        const float den = fmaf(eps, fo1, 1.0f);
        float rd = __builtin_amdgcn_rcpf(den);
        rd = fmaf(rd, fmaf(-den, rd, 1.0f), rd);
        ((float2*)s_P4[yy])[t] = make_float2(rd, eps * rd);  // entry t/2
    }
    __syncthreads();

    // ---- per-lane geometry: row = pixel, 4 h-elems/lane ----
    const int wave = tid >> 6;
    const int lane = tid & 63;
    const int row  = lane >> 4;          // 0..3
    const int il   = lane & 15;          // 0..15
    const int y    = wave * 4 + row;     // pixel y

    const int4*   __restrict__ Sy = s_spk4[y];
    const float4* __restrict__ Py = s_P4[y];

    float4 h = ((const float4*)h_init)[il];

    // ---- queues (group = 4 steps; 32 groups), weights now from LDS ----
    const int4 s0 = Sy[0];
    int4   sA  = Sy[1];
    int4   sB  = Sy[2];
    float4 wq0 = s_w4[s0.x * 16 + il];
    float4 wq1 = s_w4[s0.y * 16 + il];
    float4 wq2 = s_w4[s0.z * 16 + il];
    float4 wq3 = s_w4[s0.w * 16 + il];
    float4 PA0 = Py[0], PA1 = Py[1];     // group g
    float4 PB0 = Py[2], PB1 = Py[3];     // group g+1

    #pragma unroll 2
    for (int g = 0; g < TT / 4; ++g) {
        // group-level prefetches (all LDS; 4-8 step issue->use distance)
        const int4   s_in  = Sy[(g + 3) & 31];
        const float4 p_in0 = Py[(2 * g + 4) & 63];
        const float4 p_in1 = Py[(2 * g + 5) & 63];
        const float4 wn0 = s_w4[sA.x * 16 + il];   // rows for group g+1
        const float4 wn1 = s_w4[sA.y * 16 + il];
        const float4 wn2 = s_w4[sA.z * 16 + il];
        const float4 wn3 = s_w4[sA.w * 16 + il];

        STEP(wq0, PA0.x, PA0.y);
        STEP(wq1, PA0.z, PA0.w);
        STEP(wq2, PA1.x, PA1.y);
        STEP(wq3, PA1.z, PA1.w);

        wq0 = wn0; wq1 = wn1; wq2 = wn2; wq3 = wn3;
        PA0 = PB0; PA1 = PB1; PB0 = p_in0; PB1 = p_in1;
        sA = sB; sB = s_in;
    }

    // ---- output transpose: out[b, h, x, y] ----
    *(float4*)&s_out[y][4 * il] = h;
    __syncthreads();
    #pragma unroll
    for (int k = 0; k < 4; ++k) {
        const int idx = tid + k * 256;   // 1024 = 64 h * 16 y
        const int hh = idx >> 4, yy = idx & 15;
        out[b * (H_DIM * XY) + hh * XY + x * YDIM + yy] = s_out[yy][hh];
    }
}

extern "C" void kernel_launch(void* const* d_in, const int* in_sizes, int n_in,
                              void* d_out, int out_size, void* d_ws, size_t ws_size,
                              hipStream_t stream) {
    // inputs (setup_inputs order):
    // 0: input [B,IN,X,Y] f32 (unused)   1: spikes [B,T,X,Y] i32
    // 2: epsilon_xy [IN,X,Y] f32         3: epsilon_t_0 [T] f32
    // 4: weights [IN,H] f32              5: h_initial [H] f32
    // 6: forgetting_offset [1] f32
    const int*   spikes  = (const int*)  d_in[1];
    const float* eps_xy  = (const float*)d_in[2];
    const float* eps_t   = (const float*)d_in[3];
    const float* weights = (const float*)d_in[4];
    const float* h_init  = (const float*)d_in[5];
    const float* fo_ptr  = (const float*)d_in[6];
    float*       out     = (float*)d_out;

    const int grid = BB * XDIM;   // 256 blocks, 16 pixels each, 1/CU
    sbs_scan_kernel<<<grid, 256, 0, stream>>>(
        spikes, eps_xy, eps_t, weights, h_init, fo_ptr, out);
}